// Round 4
// baseline (2835.634 us; speedup 1.0000x reference)
//
#include <hip/hip_runtime.h>
#include <math.h>

#define N_ROWS 131072
#define DIMS 64
#define K_CODES 512

// compile-time float4 component select (valid under full unroll only)
#define COMP(v4, c) (((c)==0) ? (v4).x : (((c)==1) ? (v4).y : (((c)==2) ? (v4).z : (v4).w)))

// ---------------- K0: zero bins + c2 (numpy pairwise, bitwise) + chunk-major transpose
// cbC[c][d][kk] = codebook[c*64+kk][d]  (8 chunks x 64 dims x 64 codes, 16 KB/chunk,
// each chunk contiguous so staging is a plain coalesced 16 KB copy).
__global__ __launch_bounds__(256) void vq_init(const float* __restrict__ codebook,
                                               int* __restrict__ bins,
                                               float* __restrict__ c2g,
                                               float* __restrict__ cbC) {
  #pragma clang fp contract(off)
  const int t = threadIdx.x;
  const int b = blockIdx.x;
  if (b == 0) {
    for (int k = t; k < K_CODES; k += 256) bins[k] = 0;
    // numpy pairwise_sum, n=64: 8 accumulators over stride-8 lanes, then fixed tree.
    for (int k = t; k < K_CODES; k += 256) {
      const float* cr = codebook + k * DIMS;
      float r[8];
      #pragma unroll
      for (int j = 0; j < 8; ++j) r[j] = cr[j] * cr[j];
      for (int i = 8; i < 64; i += 8) {
        #pragma unroll
        for (int j = 0; j < 8; ++j) r[j] += cr[i + j] * cr[i + j];  // contract OFF: mul, add
      }
      c2g[k] = ((r[0] + r[1]) + (r[2] + r[3])) + ((r[4] + r[5]) + (r[6] + r[7]));
    }
  }
  // transpose slice: this block owns codes [b*8, b*8+8)
  for (int e = t; e < 512; e += 256) {
    const int k = b * 8 + (e >> 6);
    const int d = e & 63;
    cbC[(k >> 6) * 4096 + d * 64 + (k & 63)] = codebook[k * DIMS + d];
  }
}

// ---------------- K1: fused argmin + gather + STE + loss partial -----------------------
// Grid 1024 x 256 threads; 128 rows/block. Thread tile: R=8 rows x C=4 codes.
// codeg = t&15 (codes kb..kb+3 per chunk), rowg = t>>4 (rows rowg + 16*i, i=0..7).
// x rows live ENTIRELY in VGPRs (xq[8][16] float4 = 128 regs; d-loop fully unrolled so
// all indexing is static). Codebook streams through double-buffered LDS chunks
// (8 chunks x 64 codes x 64 d = 16 KB each), reg-staged: pf loads issued at chunk top
// (latency hidden under 4096 cy of fmaf), ds_write after compute, 1 barrier/chunk.
// Main loop per d: one ds_read_b128 (16 unique addrs x 4-lane broadcast, 2-way free)
// + 32 fmaf -> 0.5 B LDS per FMA (75% of LDS unit at full VALU rate). No VMEM in loop.
// M = single fmaf chain over ascending d per (row,code); d2 = (x2 - 2*M) + c2.
__global__ __launch_bounds__(256, 2) void vq_main(const float* __restrict__ latents,
                                                  const float* __restrict__ codebook,
                                                  const float* __restrict__ cbC,
                                                  const float* __restrict__ c2g,
                                                  float* __restrict__ out_st,
                                                  float* __restrict__ out_codes,
                                                  int* __restrict__ bins,
                                                  double* __restrict__ loss_part) {
  #pragma clang fp contract(off)
  __shared__ __align__(16) float sbuf[2][4096];  // 2 x 16 KB chunk buffers
  __shared__ double wsum[4];

  const int t = threadIdx.x;
  const int codeg = t & 15;
  const int rowg = t >> 4;
  const int row0 = blockIdx.x * 128;

  // ---- prologue: issue chunk-0 staging loads first (latency overlaps x loads) ----
  float4 pf[4];
  #pragma unroll
  for (int q = 0; q < 4; ++q) pf[q] = *(const float4*)&cbC[q * 1024 + t * 4];

  // x rows -> registers. Rows rowg + 16*i; 16 codeg threads hold the same row (L1 dedup).
  float4 xq[8][16];
  #pragma unroll
  for (int i = 0; i < 8; ++i) {
    const float* xr = latents + (size_t)(row0 + rowg + 16 * i) * DIMS;
    #pragma unroll
    for (int d4 = 0; d4 < 16; ++d4) xq[i][d4] = *(const float4*)&xr[d4 * 4];
  }

  // x2 per row: numpy pairwise_sum (identical values & add order as prior rounds)
  float x2v[8];
  #pragma unroll
  for (int i = 0; i < 8; ++i) {
    float r[8];
    #pragma unroll
    for (int j = 0; j < 8; ++j) { const float v = COMP(xq[i][j >> 2], j & 3); r[j] = v * v; }
    #pragma unroll
    for (int i8 = 1; i8 < 8; ++i8) {
      #pragma unroll
      for (int j = 0; j < 8; ++j) {
        const int d = i8 * 8 + j;
        const float v = COMP(xq[i][d >> 2], d & 3);
        r[j] += v * v;
      }
    }
    x2v[i] = ((r[0] + r[1]) + (r[2] + r[3])) + ((r[4] + r[5]) + (r[6] + r[7]));
  }

  // write chunk 0 into buffer 0
  #pragma unroll
  for (int q = 0; q < 4; ++q) *(float4*)&sbuf[0][q * 1024 + t * 4] = pf[q];
  __syncthreads();

  float m1[8]; int i1[8];
  #pragma unroll
  for (int i = 0; i < 8; ++i) { m1[i] = __builtin_inff(); i1[i] = 0x7fffffff; }

  int cur = 0;
  #pragma unroll 1
  for (int c = 0; c < 8; ++c) {
    // issue next chunk's staging loads (complete during the 4096-cy compute below)
    if (c < 7) {
      #pragma unroll
      for (int q = 0; q < 4; ++q)
        pf[q] = *(const float4*)&cbC[(c + 1) * 4096 + q * 1024 + t * 4];
    }

    const float* bp = sbuf[cur] + codeg * 4;
    float acc[8][4];
    #pragma unroll
    for (int i = 0; i < 8; ++i)
      #pragma unroll
      for (int j = 0; j < 4; ++j) acc[i][j] = 0.f;

    #pragma unroll
    for (int d = 0; d < 64; ++d) {          // FULL unroll: xq indexing static, LDS imm offsets
      const float4 cv = *(const float4*)&bp[d * 64];
      #pragma unroll
      for (int i = 0; i < 8; ++i) {
        const float xd = COMP(xq[i][d >> 2], d & 3);  // d ascending: one fmaf chain/(row,code)
        acc[i][0] = fmaf(xd, cv.x, acc[i][0]);
        acc[i][1] = fmaf(xd, cv.y, acc[i][1]);
        acc[i][2] = fmaf(xd, cv.z, acc[i][2]);
        acc[i][3] = fmaf(xd, cv.w, acc[i][3]);
      }
    }

    // d2 = (x2 - 2*M) + c2, one fp32 rounding per op; strict < keeps first (k ascending)
    const int kb = c * 64 + codeg * 4;
    const float4 c2v = *(const float4*)&c2g[kb];
    #pragma unroll
    for (int j = 0; j < 4; ++j) {
      const float cc = COMP(c2v, j);
      #pragma unroll
      for (int i = 0; i < 8; ++i) {
        const float tt = x2v[i] - 2.0f * acc[i][j];
        const float s = tt + cc;
        if (s < m1[i]) { m1[i] = s; i1[i] = kb + j; }
      }
    }

    // write next chunk into the other buffer (reads of sbuf[cur] are done; other buffer
    // was last read in chunk c-1, protected by that chunk's barrier)
    if (c < 7) {
      #pragma unroll
      for (int q = 0; q < 4; ++q) *(float4*)&sbuf[cur ^ 1][q * 1024 + t * 4] = pf[q];
    }
    __syncthreads();
    cur ^= 1;
  }

  // ---- merge across codeg (xor 1/2/4/8 stays within 16-lane groups); all lanes get result
  double dacc = 0.0;
  #pragma unroll
  for (int i = 0; i < 8; ++i) {
    float v = m1[i]; int idx = i1[i];
    #pragma unroll
    for (int off = 1; off < 16; off <<= 1) {
      const float ov = __shfl_xor(v, off);
      const int oi = __shfl_xor(idx, off);
      if (ov < v || (ov == v && oi < idx)) { v = ov; idx = oi; }
    }
    const int row = row0 + rowg + 16 * i;
    if (codeg == 0) {
      out_codes[row] = (float)idx;
      atomicAdd(&bins[idx], 1);
    }
    // fused gather + STE + loss: this thread owns dims [codeg*4, codeg*4+4) of its rows.
    // l re-read from latents (bitwise-same memory, L2-hot); writes coalesced 256 B/row.
    const float4 q = *(const float4*)&codebook[idx * DIMS + codeg * 4];
    const float4 l = *(const float4*)&latents[(size_t)row * DIMS + codeg * 4];
    float4 o;
    o.x = l.x + (q.x - l.x);  // straight-through, np rounding order
    o.y = l.y + (q.y - l.y);
    o.z = l.z + (q.z - l.z);
    o.w = l.w + (q.w - l.w);
    *(float4*)&out_st[(size_t)row * DIMS + codeg * 4] = o;
    const float dx = l.x - q.x, dy = l.y - q.y, dz = l.z - q.z, dw = l.w - q.w;
    dacc += (double)dx * (double)dx;
    dacc += (double)dy * (double)dy;
    dacc += (double)dz * (double)dz;
    dacc += (double)dw * (double)dw;
  }

  // block loss reduction (fp64; order-insensitive at final float cast, as prior rounds)
  #pragma unroll
  for (int off = 32; off > 0; off >>= 1) dacc += __shfl_down(dacc, off);
  if ((t & 63) == 0) wsum[t >> 6] = dacc;
  __syncthreads();
  if (t == 0) loss_part[blockIdx.x] = (wsum[0] + wsum[1]) + (wsum[2] + wsum[3]);
}

// ---------------- K3: reduce loss partials + perplexity + scalar outputs ----------
__global__ __launch_bounds__(512) void vq_finalize(const int* __restrict__ bins,
                                                   const double* __restrict__ loss_part,
                                                   float* __restrict__ out3) {
  __shared__ double red[512];
  __shared__ double redl[512];
  const int t = threadIdx.x;
  const double p = (double)bins[t] / 131072.0;
  red[t] = -p * log(p + 1e-10);
  redl[t] = loss_part[t] + loss_part[t + 512];
  __syncthreads();
  for (int s = 256; s > 0; s >>= 1) {
    if (t < s) { red[t] += red[t + s]; redl[t] += redl[t + s]; }
    __syncthreads();
  }
  if (t == 0) {
    const double mean = redl[0] / 8388608.0;
    out3[0] = (float)(0.25 * mean);  // commitment * COMMITMENT_COST
    out3[1] = (float)mean;           // codebook_loss (same squares bitwise)
    out3[2] = (float)exp(red[0]);    // perplexity
  }
}

extern "C" void kernel_launch(void* const* d_in, const int* in_sizes, int n_in,
                              void* d_out, int out_size, void* d_ws, size_t ws_size,
                              hipStream_t stream) {
  const float* latents = (const float*)d_in[0];
  const float* codebook = (const float*)d_in[1];

  float* out = (float*)d_out;
  float* out_st = out;                              // 8388608
  float* out_codes = out + (size_t)N_ROWS * DIMS;   // 131072 (codes as float)
  float* out3 = out_codes + N_ROWS;                 // 3 scalars

  char* ws = (char*)d_ws;
  double* loss_part = (double*)ws;                  // [0, 8192)       1024 doubles
  int* bins = (int*)(ws + 16384);                   // [16384, 18432)
  float* c2g = (float*)(ws + 18432);                // [18432, 20480)
  float* cbC = (float*)(ws + 20480);                // [20480, 151552) 128 KB chunk-major

  hipLaunchKernelGGL(vq_init, dim3(64), dim3(256), 0, stream,
                     codebook, bins, c2g, cbC);
  hipLaunchKernelGGL(vq_main, dim3(1024), dim3(256), 0, stream,
                     latents, codebook, cbC, c2g, out_st, out_codes, bins, loss_part);
  hipLaunchKernelGGL(vq_finalize, dim3(1), dim3(512), 0, stream,
                     bins, loss_part, out3);
}

// Round 5
// 257.977 us; speedup vs baseline: 10.9918x; 10.9918x over previous
//
#include <hip/hip_runtime.h>
#include <math.h>

#define N_ROWS 131072
#define DIMS 64
#define K_CODES 512
#define XS_STRIDE 100  // dwords; 100 % 32 == 4 -> conflict-free b128 row reads; sizes LDS to 3 blocks/CU

// compile-time float4 component select (valid under full unroll of small loops)
#define COMP(v4, c) (((c)==0) ? (v4).x : (((c)==1) ? (v4).y : (((c)==2) ? (v4).z : (v4).w)))

// ---------------- K0: zero bins + c2 (numpy pairwise, bitwise) + codebook transpose ----
// cbT[d][k] = codebook[k][d], row-major [64][512]: 8 consecutive codes at one d are
// 32 contiguous bytes -> per-lane divergent dwordx4 loads (no SMEM scalarization).
__global__ __launch_bounds__(256) void vq_init(const float* __restrict__ codebook,
                                               int* __restrict__ bins,
                                               float* __restrict__ c2g,
                                               float* __restrict__ cbT) {
  #pragma clang fp contract(off)
  const int t = threadIdx.x;
  const int b = blockIdx.x;
  if (b == 0) {
    for (int k = t; k < K_CODES; k += 256) bins[k] = 0;
    // numpy pairwise_sum, n=64: 8 accumulators over stride-8 lanes, then fixed tree.
    for (int k = t; k < K_CODES; k += 256) {
      const float* cr = codebook + k * DIMS;
      float r[8];
      #pragma unroll
      for (int j = 0; j < 8; ++j) r[j] = cr[j] * cr[j];
      for (int i = 8; i < 64; i += 8) {
        #pragma unroll
        for (int j = 0; j < 8; ++j) r[j] += cr[i + j] * cr[i + j];  // contract OFF: mul, add
      }
      c2g[k] = ((r[0] + r[1]) + (r[2] + r[3])) + ((r[4] + r[5]) + (r[6] + r[7]));
    }
  }
  // transpose slice: this block owns codes [b*8, b*8+8)
  for (int e = t; e < 512; e += 256) {
    const int k = b * 8 + (e >> 6);
    const int d = e & 63;
    cbT[d * K_CODES + k] = codebook[k * DIMS + d];
  }
}

// ---------------- K1: fused argmin + gather + STE + loss partial -----------------------
// Grid 1024 x 256; 128 rows/block; wave w owns rows [w*32, w*32+32) (waves split ROWS,
// all waves scan the same 64-code chunk in the same order -> L1-resident codebook).
// Within wave: rowg = lane&7 (rows rowg+8i, i<4), codeg = lane>>3 (8 codes per chunk).
// Thread tile R=4 rows x C=8 codes. x via conflict-free LDS b128 broadcast (stride 100).
// Codebook: per-lane VMEM, depth-1 software pipeline via named float4 sets A/B (loads
// for iter n+1 issue before iter n's 256-cy FMA block -> latency hidden; no full unroll,
// no runtime-indexed register arrays -> no scratch).
// M = single fmaf chain over ascending d per (row,code); d2 = (x2 - 2*M) + c2.
__global__ __launch_bounds__(256, 3) void vq_main(const float* __restrict__ latents,
                                                  const float* __restrict__ codebook,
                                                  const float* __restrict__ cbT,
                                                  const float* __restrict__ c2g,
                                                  float* __restrict__ out_st,
                                                  float* __restrict__ out_codes,
                                                  int* __restrict__ bins,
                                                  double* __restrict__ loss_part) {
  #pragma clang fp contract(off)
  __shared__ __align__(16) float xs[128 * XS_STRIDE];  // 51200 B -> 3 blocks/CU
  __shared__ float x2s[128];
  __shared__ double wsum[4];

  const int t = threadIdx.x;
  const int lane = t & 63;
  const int w = t >> 6;
  const int rowg = lane & 7;
  const int codeg = lane >> 3;
  const int row0 = blockIdx.x * 128;

  // stage 128x64 floats coalesced -> padded LDS (2048 float4, 8 per thread)
  {
    const float4* src = (const float4*)(latents + (size_t)row0 * DIMS);
    #pragma unroll
    for (int p = 0; p < 8; ++p) {
      const int f = p * 256 + t;
      *(float4*)&xs[(f >> 4) * XS_STRIDE + (f & 15) * 4] = src[f];
    }
  }
  __syncthreads();

  // x2 per row: numpy pairwise_sum (identical alg/order as prior passing rounds)
  if (t < 128) {
    const float* xr = xs + t * XS_STRIDE;
    float r[8];
    #pragma unroll
    for (int j = 0; j < 8; ++j) r[j] = xr[j] * xr[j];
    #pragma unroll
    for (int i = 8; i < 64; i += 8) {
      #pragma unroll
      for (int j = 0; j < 8; ++j) r[j] += xr[i + j] * xr[i + j];
    }
    x2s[t] = ((r[0] + r[1]) + (r[2] + r[3])) + ((r[4] + r[5]) + (r[6] + r[7]));
  }
  __syncthreads();

  float x2v[4];
  #pragma unroll
  for (int i = 0; i < 4; ++i) x2v[i] = x2s[w * 32 + rowg + 8 * i];

  float m1[4]; int i1[4];
  #pragma unroll
  for (int i = 0; i < 4; ++i) { m1[i] = __builtin_inff(); i1[i] = 0x7fffffff; }

  const float* cbp = cbT + codeg * 8;                       // + d*512 + c*64
  const float* xbase = xs + (w * 32 + rowg) * XS_STRIDE;    // + 8i*stride + d4*4

  float4 A0a, A0b, A1a, A1b, A2a, A2b, A3a, A3b;
  float4 B0a, B0b, B1a, B1b, B2a, B2b, B3a, B3b;

#define LOADSET(P, cc, dd4) do {                                          \
    const float* _p = cbp + (cc) * 64 + (dd4) * 4 * K_CODES;              \
    P##0a = *(const float4*)(_p + 0 * K_CODES);                           \
    P##0b = *(const float4*)(_p + 0 * K_CODES + 4);                       \
    P##1a = *(const float4*)(_p + 1 * K_CODES);                           \
    P##1b = *(const float4*)(_p + 1 * K_CODES + 4);                       \
    P##2a = *(const float4*)(_p + 2 * K_CODES);                           \
    P##2b = *(const float4*)(_p + 2 * K_CODES + 4);                       \
    P##3a = *(const float4*)(_p + 3 * K_CODES);                           \
    P##3b = *(const float4*)(_p + 3 * K_CODES + 4);                       \
  } while (0)

#define COMPUTE(P, dd4) do {                                              \
    float4 xv[4];                                                         \
    xv[0] = *(const float4*)&xbase[ 0 * XS_STRIDE + (dd4) * 4];           \
    xv[1] = *(const float4*)&xbase[ 8 * XS_STRIDE + (dd4) * 4];           \
    xv[2] = *(const float4*)&xbase[16 * XS_STRIDE + (dd4) * 4];           \
    xv[3] = *(const float4*)&xbase[24 * XS_STRIDE + (dd4) * 4];           \
    _Pragma("unroll")                                                     \
    for (int dd = 0; dd < 4; ++dd) {                                      \
      const float4 ca = (dd==0)?P##0a:(dd==1)?P##1a:(dd==2)?P##2a:P##3a;  \
      const float4 cv = (dd==0)?P##0b:(dd==1)?P##1b:(dd==2)?P##2b:P##3b;  \
      _Pragma("unroll")                                                   \
      for (int i = 0; i < 4; ++i) {                                       \
        const float xd = COMP(xv[i], dd); /* d ascending: one fmaf chain */\
        acc[i][0] = fmaf(xd, ca.x, acc[i][0]);                            \
        acc[i][1] = fmaf(xd, ca.y, acc[i][1]);                            \
        acc[i][2] = fmaf(xd, ca.z, acc[i][2]);                            \
        acc[i][3] = fmaf(xd, ca.w, acc[i][3]);                            \
        acc[i][4] = fmaf(xd, cv.x, acc[i][4]);                            \
        acc[i][5] = fmaf(xd, cv.y, acc[i][5]);                            \
        acc[i][6] = fmaf(xd, cv.z, acc[i][6]);                            \
        acc[i][7] = fmaf(xd, cv.w, acc[i][7]);                            \
      }                                                                   \
    }                                                                     \
  } while (0)

  LOADSET(A, 0, 0);  // prologue

  #pragma unroll 1
  for (int c = 0; c < 8; ++c) {
    // chunk c2 prefetch: consumed ~4096 cy later at chunk end
    const float4 c2lo = *(const float4*)&c2g[c * 64 + codeg * 8];
    const float4 c2hi = *(const float4*)&c2g[c * 64 + codeg * 8 + 4];

    float acc[4][8];
    #pragma unroll
    for (int i = 0; i < 4; ++i)
      #pragma unroll
      for (int j = 0; j < 8; ++j) acc[i][j] = 0.f;

    #pragma unroll 1
    for (int d4 = 0; d4 < 16; d4 += 2) {
      LOADSET(B, c, d4 + 1);                 // next-iter loads issue before compute
      COMPUTE(A, d4);
      {
        const int nc = (d4 < 14) ? c : ((c < 7) ? c + 1 : 7);  // clamp: tail load unused
        const int nd = (d4 < 14) ? (d4 + 2) : 0;
        LOADSET(A, nc, nd);
      }
      COMPUTE(B, d4 + 1);
    }

    // d2 = (x2 - 2*M) + c2, one fp32 rounding per op; strict < keeps first (k ascending)
    #pragma unroll
    for (int j = 0; j < 8; ++j) {
      const float cc2 = (j < 4) ? COMP(c2lo, j & 3) : COMP(c2hi, j & 3);
      const int k = c * 64 + codeg * 8 + j;
      #pragma unroll
      for (int i = 0; i < 4; ++i) {
        const float tt = x2v[i] - 2.0f * acc[i][j];
        const float s = tt + cc2;
        if (s < m1[i]) { m1[i] = s; i1[i] = k; }
      }
    }
  }
#undef LOADSET
#undef COMPUTE

  // merge across codeg (xor 8/16/32 flips codeg bits only); min val, tie -> min k.
  // Butterfly leaves every lane holding its rowg's winner. Then fused epilogue:
  // thread owns dims [codeg*8, codeg*8+8) of its 4 rows.
  double dacc = 0.0;
  #pragma unroll
  for (int i = 0; i < 4; ++i) {
    float v = m1[i]; int idx = i1[i];
    #pragma unroll
    for (int off = 8; off < 64; off <<= 1) {
      const float ov = __shfl_xor(v, off);
      const int oi = __shfl_xor(idx, off);
      if (ov < v || (ov == v && oi < idx)) { v = ov; idx = oi; }
    }
    const int rl = w * 32 + rowg + 8 * i;   // block-local row
    const int row = row0 + rl;
    if (codeg == 0) {
      out_codes[row] = (float)idx;
      atomicAdd(&bins[idx], 1);
    }
    const float4 q0 = *(const float4*)&codebook[idx * DIMS + codeg * 8];
    const float4 q1 = *(const float4*)&codebook[idx * DIMS + codeg * 8 + 4];
    const float4 l0 = *(const float4*)&xs[rl * XS_STRIDE + codeg * 8];
    const float4 l1 = *(const float4*)&xs[rl * XS_STRIDE + codeg * 8 + 4];
    float4 o0, o1;
    o0.x = l0.x + (q0.x - l0.x);  // straight-through, np rounding order
    o0.y = l0.y + (q0.y - l0.y);
    o0.z = l0.z + (q0.z - l0.z);
    o0.w = l0.w + (q0.w - l0.w);
    o1.x = l1.x + (q1.x - l1.x);
    o1.y = l1.y + (q1.y - l1.y);
    o1.z = l1.z + (q1.z - l1.z);
    o1.w = l1.w + (q1.w - l1.w);
    *(float4*)&out_st[(size_t)row * DIMS + codeg * 8] = o0;
    *(float4*)&out_st[(size_t)row * DIMS + codeg * 8 + 4] = o1;
    const float d0 = l0.x - q0.x, d1 = l0.y - q0.y, d2 = l0.z - q0.z, d3 = l0.w - q0.w;
    const float d4_ = l1.x - q1.x, d5 = l1.y - q1.y, d6 = l1.z - q1.z, d7 = l1.w - q1.w;
    dacc += (double)d0 * (double)d0;
    dacc += (double)d1 * (double)d1;
    dacc += (double)d2 * (double)d2;
    dacc += (double)d3 * (double)d3;
    dacc += (double)d4_ * (double)d4_;
    dacc += (double)d5 * (double)d5;
    dacc += (double)d6 * (double)d6;
    dacc += (double)d7 * (double)d7;
  }

  // block loss reduction (fp64; order-insensitive at final float cast, as prior rounds)
  #pragma unroll
  for (int off = 32; off > 0; off >>= 1) dacc += __shfl_down(dacc, off);
  if (lane == 0) wsum[w] = dacc;
  __syncthreads();
  if (t == 0) loss_part[blockIdx.x] = (wsum[0] + wsum[1]) + (wsum[2] + wsum[3]);
}

// ---------------- K3: reduce loss partials + perplexity + scalar outputs ----------
__global__ __launch_bounds__(512) void vq_finalize(const int* __restrict__ bins,
                                                   const double* __restrict__ loss_part,
                                                   float* __restrict__ out3) {
  __shared__ double red[512];
  __shared__ double redl[512];
  const int t = threadIdx.x;
  const double p = (double)bins[t] / 131072.0;
  red[t] = -p * log(p + 1e-10);
  redl[t] = loss_part[t] + loss_part[t + 512];
  __syncthreads();
  for (int s = 256; s > 0; s >>= 1) {
    if (t < s) { red[t] += red[t + s]; redl[t] += redl[t + s]; }
    __syncthreads();
  }
  if (t == 0) {
    const double mean = redl[0] / 8388608.0;
    out3[0] = (float)(0.25 * mean);  // commitment * COMMITMENT_COST
    out3[1] = (float)mean;           // codebook_loss (same squares bitwise)
    out3[2] = (float)exp(red[0]);    // perplexity
  }
}

extern "C" void kernel_launch(void* const* d_in, const int* in_sizes, int n_in,
                              void* d_out, int out_size, void* d_ws, size_t ws_size,
                              hipStream_t stream) {
  const float* latents = (const float*)d_in[0];
  const float* codebook = (const float*)d_in[1];

  float* out = (float*)d_out;
  float* out_st = out;                              // 8388608
  float* out_codes = out + (size_t)N_ROWS * DIMS;   // 131072 (codes as float)
  float* out3 = out_codes + N_ROWS;                 // 3 scalars

  char* ws = (char*)d_ws;
  double* loss_part = (double*)ws;                  // [0, 8192)       1024 doubles
  int* bins = (int*)(ws + 16384);                   // [16384, 18432)
  float* c2g = (float*)(ws + 18432);                // [18432, 20480)
  float* cbT = (float*)(ws + 20480);                // [20480, 151552) 128 KB transposed

  hipLaunchKernelGGL(vq_init, dim3(64), dim3(256), 0, stream,
                     codebook, bins, c2g, cbT);
  hipLaunchKernelGGL(vq_main, dim3(1024), dim3(256), 0, stream,
                     latents, codebook, cbT, c2g, out_st, out_codes, bins, loss_part);
  hipLaunchKernelGGL(vq_finalize, dim3(1), dim3(512), 0, stream,
                     bins, loss_part, out3);
}

// Round 6
// 169.855 us; speedup vs baseline: 16.6945x; 1.5188x over previous
//
#include <hip/hip_runtime.h>
#include <math.h>

#define N_ROWS 131072
#define DIMS 64
#define K_CODES 512
#define XS_STRIDE 68

typedef __attribute__((ext_vector_type(8))) short bf16x8;
typedef __attribute__((ext_vector_type(4))) float f32x4;

union B8 { uint4 u; bf16x8 h; };

// RNE float->bf16 pack (two floats -> one uint, low=first)
__device__ inline unsigned bpack(float a, float b) {
  unsigned ua = __float_as_uint(a), ub = __float_as_uint(b);
  ua = (ua + 0x7FFFu + ((ua >> 16) & 1u)) >> 16;
  ub = (ub + 0x7FFFu + ((ub >> 16) & 1u)) >> 16;
  return ua | (ub << 16);
}

// exact reference dot: single fmaf chain over ascending d (bitwise as prior rounds)
__device__ inline float exact_dot(const float* __restrict__ xr, const float* __restrict__ cr) {
  float m = 0.f;
  #pragma unroll
  for (int d4 = 0; d4 < 16; ++d4) {
    const float4 c = *(const float4*)&cr[d4 * 4];
    const float4 x = *(const float4*)&xr[d4 * 4];
    m = fmaf(x.x, c.x, m);
    m = fmaf(x.y, c.y, m);
    m = fmaf(x.z, c.z, m);
    m = fmaf(x.w, c.w, m);
  }
  return m;
}

// ---------------- K0: bins zero + exact c2 (numpy pairwise) + cmax2 + bf16 B-frag build
// cbB layout: entry e = ct*128 + lane*2 + half  (uint4 = 8 bf16)
//   code = ct*16 + (lane&15), dims [(lane>>4)*8 + half*32 .. +8)
// -> in vq_main, per code-tile ct each lane loads entries (ct*64+lane)*2 + {0,1}:
//    fully coalesced, and the B-fragment of mfma_f32_16x16x32_bf16.
__global__ __launch_bounds__(256) void vq_init(const float* __restrict__ codebook,
                                               int* __restrict__ bins,
                                               float* __restrict__ c2g,
                                               float* __restrict__ cmax2p,
                                               uint4* __restrict__ cbB) {
  #pragma clang fp contract(off)
  __shared__ float smax[256];
  const int t = threadIdx.x;
  const int b = blockIdx.x;
  if (b == 0) {
    for (int k = t; k < K_CODES; k += 256) bins[k] = 0;
    float lmax = 0.f;
    // numpy pairwise_sum, n=64: 8 accumulators over stride-8 lanes, then fixed tree.
    for (int k = t; k < K_CODES; k += 256) {
      const float* cr = codebook + k * DIMS;
      float r[8];
      #pragma unroll
      for (int j = 0; j < 8; ++j) r[j] = cr[j] * cr[j];
      for (int i = 8; i < 64; i += 8) {
        #pragma unroll
        for (int j = 0; j < 8; ++j) r[j] += cr[i + j] * cr[i + j];  // contract OFF
      }
      const float c2 = ((r[0] + r[1]) + (r[2] + r[3])) + ((r[4] + r[5]) + (r[6] + r[7]));
      c2g[k] = c2;
      lmax = fmaxf(lmax, c2);
    }
    smax[t] = lmax;
    __syncthreads();
    for (int s = 128; s > 0; s >>= 1) {
      if (t < s) smax[t] = fmaxf(smax[t], smax[t + s]);
      __syncthreads();
    }
    if (t == 0) *cmax2p = smax[0];
  }
  // bf16 fragment table: 4096 uint4 entries over blocks 0..15
  if (b < 16) {
    const int e = b * 256 + t;
    const int ct = e >> 7;
    const int q = e & 127;
    const int lane_id = q >> 1;
    const int half = q & 1;
    const int code = ct * 16 + (lane_id & 15);
    const int dbase = ((lane_id >> 4) * 8) + half * 32;
    const float* src = codebook + code * DIMS + dbase;
    const float4 a = *(const float4*)&src[0];
    const float4 c = *(const float4*)&src[4];
    uint4 u;
    u.x = bpack(a.x, a.y);
    u.y = bpack(a.z, a.w);
    u.z = bpack(c.x, c.y);
    u.w = bpack(c.z, c.w);
    cbB[e] = u;
  }
}

// ---------------- K1: MFMA approx scores -> candidate set -> exact rescore -> outputs
// Grid 2048 x 256 (64 rows/block, wave w owns rows [w*16,(w+1)*16) as one MFMA M-tile).
// Sweep1: 32 code-tiles x 2 MFMA (K=64) -> approx d2, per-row approx min.
// thr[row] = min + E(row), E = rigorous bf16-error bound *2 (two-sided) + slack.
// Sweep2: recompute (deterministic), collect k with d2hat <= thr into per-row lists.
// Rescore: exact fmaf-chain d2 (bit-identical to prior passing rounds) over candidates
// only; first-min tie semantics via (value, min k). Overflow rows (>16 cands): exact
// wave-parallel full 512-scan. Then fused gather/STE/loss epilogue.
__global__ __launch_bounds__(256) void vq_main(const float* __restrict__ latents,
                                               const float* __restrict__ codebook,
                                               const uint4* __restrict__ cbB,
                                               const float* __restrict__ c2g,
                                               const float* __restrict__ cmax2p,
                                               float* __restrict__ out_st,
                                               float* __restrict__ out_codes,
                                               int* __restrict__ bins,
                                               double* __restrict__ loss_part) {
  #pragma clang fp contract(off)
  __shared__ __align__(16) float xs[64 * XS_STRIDE];  // 17408 B
  __shared__ float x2s[64];
  __shared__ float c2s[K_CODES];
  __shared__ float thr[64];
  __shared__ int cand_cnt[64];
  __shared__ int cand_k[64][16];
  __shared__ int rowk[64];
  __shared__ float pvv[4][64];
  __shared__ int pkk[4][64];
  __shared__ int ovf_rows[64];
  __shared__ int ovf_cnt;
  __shared__ double wsum[4];

  const int t = threadIdx.x;
  const int lane = t & 63;
  const int w = t >> 6;
  const int row0 = blockIdx.x * 64;

  // stage latents tile (coalesced) + c2 + zero counters
  {
    const float4* src = (const float4*)(latents + (size_t)row0 * DIMS);
    #pragma unroll
    for (int p = 0; p < 4; ++p) {
      const int f = p * 256 + t;
      *(float4*)&xs[(f >> 4) * XS_STRIDE + (f & 15) * 4] = src[f];
    }
    c2s[t] = c2g[t];
    c2s[t + 256] = c2g[t + 256];
    if (t < 64) cand_cnt[t] = 0;
    if (t == 0) ovf_cnt = 0;
  }
  __syncthreads();

  // exact x2 per row: numpy pairwise_sum (identical alg/order as prior passing rounds)
  if (t < 64) {
    const float* xr = xs + t * XS_STRIDE;
    float r[8];
    #pragma unroll
    for (int j = 0; j < 8; ++j) r[j] = xr[j] * xr[j];
    #pragma unroll
    for (int i = 8; i < 64; i += 8) {
      #pragma unroll
      for (int j = 0; j < 8; ++j) r[j] += xr[i + j] * xr[i + j];
    }
    x2s[t] = ((r[0] + r[1]) + (r[2] + r[3])) + ((r[4] + r[5]) + (r[6] + r[7]));
  }
  __syncthreads();

  // ---- build A fragments (16 rows x K=64 as 2 frags): lane holds
  // A[m=lane&15][k=(lane>>4)*8 + j] (+32 for frag1); RNE bf16.
  const int m = lane & 15;
  const int kq = lane >> 4;
  bf16x8 af0, af1;
  {
    const float* xr = xs + (w * 16 + m) * XS_STRIDE + kq * 8;
    const float4 a0 = *(const float4*)&xr[0];
    const float4 a1 = *(const float4*)&xr[4];
    const float4 b0 = *(const float4*)&xr[32];
    const float4 b1 = *(const float4*)&xr[36];
    B8 pa, pb;
    pa.u.x = bpack(a0.x, a0.y); pa.u.y = bpack(a0.z, a0.w);
    pa.u.z = bpack(a1.x, a1.y); pa.u.w = bpack(a1.z, a1.w);
    pb.u.x = bpack(b0.x, b0.y); pb.u.y = bpack(b0.z, b0.w);
    pb.u.z = bpack(b1.x, b1.y); pb.u.w = bpack(b1.z, b1.w);
    af0 = pa.h;
    af1 = pb.h;
  }

  // C/D mapping (HW-verified): col = lane&15 (code), row = (lane>>4)*4 + reg.
  float x2r[4];
  int rowc[4];
  #pragma unroll
  for (int j = 0; j < 4; ++j) { rowc[j] = w * 16 + kq * 4 + j; x2r[j] = x2s[rowc[j]]; }
  const float cmax = sqrtf(*cmax2p) * 1.0001f;

  // ---- sweep 1: approx min per row ----
  float mv0 = __builtin_inff(), mv1 = __builtin_inff(), mv2 = __builtin_inff(), mv3 = __builtin_inff();
  #pragma unroll 1
  for (int ct = 0; ct < 32; ++ct) {
    B8 b0, b1;
    b0.u = cbB[(ct * 64 + lane) * 2 + 0];
    b1.u = cbB[(ct * 64 + lane) * 2 + 1];
    f32x4 acc = {0.f, 0.f, 0.f, 0.f};
    acc = __builtin_amdgcn_mfma_f32_16x16x32_bf16(af0, b0.h, acc, 0, 0, 0);
    acc = __builtin_amdgcn_mfma_f32_16x16x32_bf16(af1, b1.h, acc, 0, 0, 0);
    const float c2v = c2s[ct * 16 + m];
    const float s0 = (x2r[0] - 2.0f * acc[0]) + c2v;
    const float s1 = (x2r[1] - 2.0f * acc[1]) + c2v;
    const float s2 = (x2r[2] - 2.0f * acc[2]) + c2v;
    const float s3 = (x2r[3] - 2.0f * acc[3]) + c2v;
    mv0 = fminf(mv0, s0); mv1 = fminf(mv1, s1);
    mv2 = fminf(mv2, s2); mv3 = fminf(mv3, s3);
  }
  // reduce min across the 16 lanes sharing rows (xor 1,2,4,8 flips lane&15 only)
  #pragma unroll
  for (int off = 1; off < 16; off <<= 1) {
    mv0 = fminf(mv0, __shfl_xor(mv0, off));
    mv1 = fminf(mv1, __shfl_xor(mv1, off));
    mv2 = fminf(mv2, __shfl_xor(mv2, off));
    mv3 = fminf(mv3, __shfl_xor(mv3, off));
  }
  if (m == 0) {
    // two-sided margin: |d2hat - d2exact| <= 2*||x||*cmax*2^-7*(1+eps); E = 2x that + slack
    thr[rowc[0]] = mv0 + (sqrtf(x2r[0]) * cmax * 0.0427f + 1e-3f);
    thr[rowc[1]] = mv1 + (sqrtf(x2r[1]) * cmax * 0.0427f + 1e-3f);
    thr[rowc[2]] = mv2 + (sqrtf(x2r[2]) * cmax * 0.0427f + 1e-3f);
    thr[rowc[3]] = mv3 + (sqrtf(x2r[3]) * cmax * 0.0427f + 1e-3f);
  }
  __syncthreads();

  // ---- sweep 2: deterministic recompute, collect candidates ----
  float thrr[4];
  #pragma unroll
  for (int j = 0; j < 4; ++j) thrr[j] = thr[rowc[j]];
  #pragma unroll 1
  for (int ct = 0; ct < 32; ++ct) {
    B8 b0, b1;
    b0.u = cbB[(ct * 64 + lane) * 2 + 0];
    b1.u = cbB[(ct * 64 + lane) * 2 + 1];
    f32x4 acc = {0.f, 0.f, 0.f, 0.f};
    acc = __builtin_amdgcn_mfma_f32_16x16x32_bf16(af0, b0.h, acc, 0, 0, 0);
    acc = __builtin_amdgcn_mfma_f32_16x16x32_bf16(af1, b1.h, acc, 0, 0, 0);
    const float c2v = c2s[ct * 16 + m];
    const int k = ct * 16 + m;
    #pragma unroll
    for (int j = 0; j < 4; ++j) {
      const float s = (x2r[j] - 2.0f * acc[j]) + c2v;
      if (s <= thrr[j]) {
        const int pos = atomicAdd(&cand_cnt[rowc[j]], 1);
        if (pos < 16) cand_k[rowc[j]][pos] = k;
      }
    }
  }
  __syncthreads();

  // ---- exact rescore: 4 threads per row (phase = t>>6), candidates strided ----
  {
    const int rr = t & 63;
    const int ph = t >> 6;
    const int cnt = cand_cnt[rr];
    float bv = __builtin_inff();
    int bk = 0x7fffffff;
    if (cnt <= 16) {
      const float* xr = xs + rr * XS_STRIDE;
      const float x2e = x2s[rr];
      for (int c = ph; c < cnt; c += 4) {
        const int k = cand_k[rr][c];
        const float M = exact_dot(xr, codebook + k * DIMS);
        const float s = (x2e - 2.0f * M) + c2s[k];
        if (s < bv || (s == bv && k < bk)) { bv = s; bk = k; }
      }
    } else if (ph == 0) {
      const int p = atomicAdd(&ovf_cnt, 1);
      ovf_rows[p] = rr;
    }
    pvv[ph][rr] = bv;
    pkk[ph][rr] = bk;
  }
  __syncthreads();
  if (t < 64) {
    float bv = pvv[0][t];
    int bk = pkk[0][t];
    #pragma unroll
    for (int ph = 1; ph < 4; ++ph) {
      const float v = pvv[ph][t];
      const int k = pkk[ph][t];
      if (v < bv || (v == bv && k < bk)) { bv = v; bk = k; }
    }
    rowk[t] = bk;
  }
  __syncthreads();

  // overflow rows (rare): exact wave-parallel full scan by wave 0
  if (w == 0) {
    const int no = ovf_cnt;
    for (int o = 0; o < no; ++o) {
      const int rr = ovf_rows[o];
      const float* xr = xs + rr * XS_STRIDE;
      const float x2e = x2s[rr];
      float bv = __builtin_inff();
      int bk = 0x7fffffff;
      for (int k = lane; k < K_CODES; k += 64) {
        const float M = exact_dot(xr, codebook + k * DIMS);
        const float s = (x2e - 2.0f * M) + c2s[k];
        if (s < bv || (s == bv && k < bk)) { bv = s; bk = k; }
      }
      #pragma unroll
      for (int off = 1; off < 64; off <<= 1) {
        const float ov = __shfl_xor(bv, off);
        const int oi = __shfl_xor(bk, off);
        if (ov < bv || (ov == bv && oi < bk)) { bv = ov; bk = oi; }
      }
      if (lane == 0) rowk[rr] = bk;
    }
  }
  __syncthreads();

  // ---- outputs: codes + bins + fused STE/loss epilogue ----
  if (t < 64) {
    const int k = rowk[t];
    out_codes[row0 + t] = (float)k;
    atomicAdd(&bins[k], 1);
  }
  double dacc = 0.0;
  {
    float4* dst = (float4*)out_st + (size_t)row0 * 16;
    #pragma unroll
    for (int p = 0; p < 4; ++p) {
      const int f = p * 256 + t;
      const int r = f >> 4;
      const int d4 = f & 15;
      const int k = rowk[r];
      const float4 q = *(const float4*)&codebook[k * DIMS + d4 * 4];
      const float4 l = *(const float4*)&xs[r * XS_STRIDE + d4 * 4];
      float4 o;
      o.x = l.x + (q.x - l.x);  // straight-through, np rounding order
      o.y = l.y + (q.y - l.y);
      o.z = l.z + (q.z - l.z);
      o.w = l.w + (q.w - l.w);
      dst[f] = o;
      const float dx = l.x - q.x, dy = l.y - q.y, dz = l.z - q.z, dw = l.w - q.w;
      dacc += (double)dx * (double)dx;
      dacc += (double)dy * (double)dy;
      dacc += (double)dz * (double)dz;
      dacc += (double)dw * (double)dw;
    }
  }
  #pragma unroll
  for (int off = 32; off > 0; off >>= 1) dacc += __shfl_down(dacc, off);
  if (lane == 0) wsum[w] = dacc;
  __syncthreads();
  if (t == 0) loss_part[blockIdx.x] = (wsum[0] + wsum[1]) + (wsum[2] + wsum[3]);
}

// ---------------- K3: reduce loss partials + perplexity + scalar outputs ----------
__global__ __launch_bounds__(512) void vq_finalize(const int* __restrict__ bins,
                                                   const double* __restrict__ loss_part,
                                                   float* __restrict__ out3) {
  __shared__ double red[512];
  __shared__ double redl[512];
  const int t = threadIdx.x;
  const double p = (double)bins[t] / 131072.0;
  red[t] = -p * log(p + 1e-10);
  redl[t] = (loss_part[t] + loss_part[t + 512]) + (loss_part[t + 1024] + loss_part[t + 1536]);
  __syncthreads();
  for (int s = 256; s > 0; s >>= 1) {
    if (t < s) { red[t] += red[t + s]; redl[t] += redl[t + s]; }
    __syncthreads();
  }
  if (t == 0) {
    const double mean = redl[0] / 8388608.0;
    out3[0] = (float)(0.25 * mean);  // commitment * COMMITMENT_COST
    out3[1] = (float)mean;           // codebook_loss (same squares bitwise)
    out3[2] = (float)exp(red[0]);    // perplexity
  }
}

extern "C" void kernel_launch(void* const* d_in, const int* in_sizes, int n_in,
                              void* d_out, int out_size, void* d_ws, size_t ws_size,
                              hipStream_t stream) {
  const float* latents = (const float*)d_in[0];
  const float* codebook = (const float*)d_in[1];

  float* out = (float*)d_out;
  float* out_st = out;                              // 8388608
  float* out_codes = out + (size_t)N_ROWS * DIMS;   // 131072 (codes as float)
  float* out3 = out_codes + N_ROWS;                 // 3 scalars

  char* ws = (char*)d_ws;
  double* loss_part = (double*)ws;                  // [0, 16384)       2048 doubles
  int* bins = (int*)(ws + 16384);                   // [16384, 18432)
  float* c2g = (float*)(ws + 18432);                // [18432, 20480)
  float* cmax2 = (float*)(ws + 20480);              // [20480, 20484)
  uint4* cbB = (uint4*)(ws + 21504);                // [21504, 87040)   64 KB bf16 frags

  hipLaunchKernelGGL(vq_init, dim3(16), dim3(256), 0, stream,
                     codebook, bins, c2g, cmax2, cbB);
  hipLaunchKernelGGL(vq_main, dim3(2048), dim3(256), 0, stream,
                     latents, codebook, cbB, c2g, cmax2, out_st, out_codes, bins, loss_part);
  hipLaunchKernelGGL(vq_finalize, dim3(1), dim3(512), 0, stream,
                     bins, loss_part, out3);
}

// Round 7
// 152.607 us; speedup vs baseline: 18.5812x; 1.1130x over previous
//
#include <hip/hip_runtime.h>
#include <math.h>

#define N_ROWS 131072
#define DIMS 64
#define K_CODES 512
#define XS_STRIDE 68

typedef __attribute__((ext_vector_type(8))) short bf16x8;
typedef __attribute__((ext_vector_type(4))) float f32x4;

union B8 { uint4 u; bf16x8 h; };

// RNE float->bf16 pack (two floats -> one uint, low=first)
__device__ inline unsigned bpack(float a, float b) {
  unsigned ua = __float_as_uint(a), ub = __float_as_uint(b);
  ua = (ua + 0x7FFFu + ((ua >> 16) & 1u)) >> 16;
  ub = (ub + 0x7FFFu + ((ub >> 16) & 1u)) >> 16;
  return ua | (ub << 16);
}

// exact reference dot: single fmaf chain over ascending d (bitwise as prior rounds)
__device__ inline float exact_dot(const float* __restrict__ xr, const float* __restrict__ cr) {
  float m = 0.f;
  #pragma unroll
  for (int d4 = 0; d4 < 16; ++d4) {
    const float4 c = *(const float4*)&cr[d4 * 4];
    const float4 x = *(const float4*)&xr[d4 * 4];
    m = fmaf(x.x, c.x, m);
    m = fmaf(x.y, c.y, m);
    m = fmaf(x.z, c.z, m);
    m = fmaf(x.w, c.w, m);
  }
  return m;
}

// ---------------- K0: bins zero + exact c2 (numpy pairwise) + cmax2 + bf16 B-frag build
// cbB layout (unchanged from passing round): entry e = ct*128 + lane*2 + half;
//   code = ct*16 + (lane&15), dims [(lane>>4)*8 + half*32 .. +8).
__global__ __launch_bounds__(256) void vq_init(const float* __restrict__ codebook,
                                               int* __restrict__ bins,
                                               float* __restrict__ c2g,
                                               float* __restrict__ cmax2p,
                                               uint4* __restrict__ cbB) {
  #pragma clang fp contract(off)
  __shared__ float smax[256];
  const int t = threadIdx.x;
  const int b = blockIdx.x;
  if (b == 0) {
    for (int k = t; k < K_CODES; k += 256) bins[k] = 0;
    float lmax = 0.f;
    // numpy pairwise_sum, n=64: 8 accumulators over stride-8 lanes, then fixed tree.
    for (int k = t; k < K_CODES; k += 256) {
      const float* cr = codebook + k * DIMS;
      float r[8];
      #pragma unroll
      for (int j = 0; j < 8; ++j) r[j] = cr[j] * cr[j];
      for (int i = 8; i < 64; i += 8) {
        #pragma unroll
        for (int j = 0; j < 8; ++j) r[j] += cr[i + j] * cr[i + j];  // contract OFF
      }
      const float c2 = ((r[0] + r[1]) + (r[2] + r[3])) + ((r[4] + r[5]) + (r[6] + r[7]));
      c2g[k] = c2;
      lmax = fmaxf(lmax, c2);
    }
    smax[t] = lmax;
    __syncthreads();
    for (int s = 128; s > 0; s >>= 1) {
      if (t < s) smax[t] = fmaxf(smax[t], smax[t + s]);
      __syncthreads();
    }
    if (t == 0) *cmax2p = smax[0];
  }
  // bf16 fragment table: 4096 uint4 entries over blocks 0..15
  if (b < 16) {
    const int e = b * 256 + t;
    const int ct = e >> 7;
    const int q = e & 127;
    const int lane_id = q >> 1;
    const int half = q & 1;
    const int code = ct * 16 + (lane_id & 15);
    const int dbase = ((lane_id >> 4) * 8) + half * 32;
    const float* src = codebook + code * DIMS + dbase;
    const float4 a = *(const float4*)&src[0];
    const float4 c = *(const float4*)&src[4];
    uint4 u;
    u.x = bpack(a.x, a.y);
    u.y = bpack(a.z, a.w);
    u.z = bpack(c.x, c.y);
    u.w = bpack(c.z, c.w);
    cbB[e] = u;
  }
}

// ---------------- K1: MFMA approx scores -> candidates -> exact rescore -> outputs
// Grid 2048 x 256 (64 rows/block). NEW mapping: wave w covers ALL 64 rows (4 M-tiles)
// but only ITS code quarter (8 code-tiles, ct = w*8..w*8+7). Per sweep iteration one
// B-load pair feeds 8 MFMAs (4 tiles x K=64) -> 4x less cbB L2 traffic (268 MB total)
// and a 4x shorter dependent-VMEM chain; light depth-1 prefetch (16 regs) on top.
// Per-row partial mins merge across waves via LDS. Sweep2 recomputes deterministically
// and collects candidates vs thr = min + rigorous bf16 margin; exact fmaf-chain rescore
// (bit-identical to prior passing rounds) picks the true first-min winner.
__global__ __launch_bounds__(256, 4) void vq_main(const float* __restrict__ latents,
                                                  const float* __restrict__ codebook,
                                                  const uint4* __restrict__ cbB,
                                                  const float* __restrict__ c2g,
                                                  const float* __restrict__ cmax2p,
                                                  float* __restrict__ out_st,
                                                  float* __restrict__ out_codes,
                                                  int* __restrict__ bins,
                                                  double* __restrict__ loss_part) {
  #pragma clang fp contract(off)
  __shared__ __align__(16) float xs[64 * XS_STRIDE];  // 17408 B
  __shared__ float x2s[64];
  __shared__ float c2s[K_CODES];
  __shared__ float thr[64];
  __shared__ float pmin[4][64];
  __shared__ int cand_cnt[64];
  __shared__ int cand_k[64][16];
  __shared__ int rowk[64];
  __shared__ float pvv[4][64];
  __shared__ int pkk[4][64];
  __shared__ int ovf_rows[64];
  __shared__ int ovf_cnt;
  __shared__ double wsum[4];

  const int t = threadIdx.x;
  const int lane = t & 63;
  const int w = t >> 6;
  const int m = lane & 15;
  const int kq = lane >> 4;
  const int row0 = blockIdx.x * 64;

  // stage latents tile (coalesced) + c2 + zero counters
  {
    const float4* src = (const float4*)(latents + (size_t)row0 * DIMS);
    #pragma unroll
    for (int p = 0; p < 4; ++p) {
      const int f = p * 256 + t;
      *(float4*)&xs[(f >> 4) * XS_STRIDE + (f & 15) * 4] = src[f];
    }
    c2s[t] = c2g[t];
    c2s[t + 256] = c2g[t + 256];
    if (t < 64) cand_cnt[t] = 0;
    if (t == 0) ovf_cnt = 0;
  }
  __syncthreads();

  // exact x2 per row: numpy pairwise_sum (identical alg/order as prior passing rounds)
  if (t < 64) {
    const float* xr = xs + t * XS_STRIDE;
    float r[8];
    #pragma unroll
    for (int j = 0; j < 8; ++j) r[j] = xr[j] * xr[j];
    #pragma unroll
    for (int i = 8; i < 64; i += 8) {
      #pragma unroll
      for (int j = 0; j < 8; ++j) r[j] += xr[i + j] * xr[i + j];
    }
    x2s[t] = ((r[0] + r[1]) + (r[2] + r[3])) + ((r[4] + r[5]) + (r[6] + r[7]));
  }
  __syncthreads();

  // ---- A fragments for ALL 4 M-tiles: lane holds A[row=T*16+m][k=kq*8+j] (+32 frag1)
  bf16x8 af0[4], af1[4];
  #pragma unroll
  for (int T = 0; T < 4; ++T) {
    const float* xr = xs + (T * 16 + m) * XS_STRIDE + kq * 8;
    const float4 a0 = *(const float4*)&xr[0];
    const float4 a1 = *(const float4*)&xr[4];
    const float4 b0 = *(const float4*)&xr[32];
    const float4 b1 = *(const float4*)&xr[36];
    B8 pa, pb;
    pa.u.x = bpack(a0.x, a0.y); pa.u.y = bpack(a0.z, a0.w);
    pa.u.z = bpack(a1.x, a1.y); pa.u.w = bpack(a1.z, a1.w);
    pb.u.x = bpack(b0.x, b0.y); pb.u.y = bpack(b0.z, b0.w);
    pb.u.z = bpack(b1.x, b1.y); pb.u.w = bpack(b1.z, b1.w);
    af0[T] = pa.h;
    af1[T] = pb.h;
  }

  // C/D mapping (HW-verified): col = lane&15 (code), row-in-tile = kq*4 + reg.
  float x2r[4][4];
  #pragma unroll
  for (int T = 0; T < 4; ++T)
    #pragma unroll
    for (int j = 0; j < 4; ++j) x2r[T][j] = x2s[T * 16 + kq * 4 + j];
  const float cmax = sqrtf(*cmax2p) * 1.0001f;
  const int ct0 = w * 8;

  // ---- sweep 1: approx min per row over this wave's code quarter ----
  float mv[4][4];
  #pragma unroll
  for (int T = 0; T < 4; ++T)
    #pragma unroll
    for (int j = 0; j < 4; ++j) mv[T][j] = __builtin_inff();

  B8 cb0, cb1, nb0, nb1;
  cb0.u = cbB[ct0 * 128 + lane * 2 + 0];
  cb1.u = cbB[ct0 * 128 + lane * 2 + 1];
  #pragma unroll 1
  for (int q = 0; q < 8; ++q) {
    const int ct = ct0 + q;
    if (q < 7) {
      nb0.u = cbB[(ct + 1) * 128 + lane * 2 + 0];
      nb1.u = cbB[(ct + 1) * 128 + lane * 2 + 1];
    }
    const float c2v = c2s[ct * 16 + m];
    #pragma unroll
    for (int T = 0; T < 4; ++T) {
      f32x4 acc = {0.f, 0.f, 0.f, 0.f};
      acc = __builtin_amdgcn_mfma_f32_16x16x32_bf16(af0[T], cb0.h, acc, 0, 0, 0);
      acc = __builtin_amdgcn_mfma_f32_16x16x32_bf16(af1[T], cb1.h, acc, 0, 0, 0);
      #pragma unroll
      for (int j = 0; j < 4; ++j) {
        const float s = (x2r[T][j] - 2.0f * acc[j]) + c2v;
        mv[T][j] = fminf(mv[T][j], s);
      }
    }
    cb0 = nb0;
    cb1 = nb1;
  }
  // reduce min across the 16 lanes sharing rows (xor 1,2,4,8 flips m only)
  #pragma unroll
  for (int T = 0; T < 4; ++T)
    #pragma unroll
    for (int j = 0; j < 4; ++j) {
      float v = mv[T][j];
      #pragma unroll
      for (int off = 1; off < 16; off <<= 1) v = fminf(v, __shfl_xor(v, off));
      mv[T][j] = v;
    }
  if (m == 0) {
    #pragma unroll
    for (int T = 0; T < 4; ++T)
      #pragma unroll
      for (int j = 0; j < 4; ++j) pmin[w][T * 16 + kq * 4 + j] = mv[T][j];
  }
  __syncthreads();
  if (t < 64) {
    const float gmin = fminf(fminf(pmin[0][t], pmin[1][t]), fminf(pmin[2][t], pmin[3][t]));
    // two-sided bf16 margin (proven coefficient from passing round) + slack
    thr[t] = gmin + (sqrtf(x2s[t]) * cmax * 0.0427f + 1e-3f);
  }
  __syncthreads();

  // ---- sweep 2: deterministic recompute over the same quarter, collect candidates ----
  float thrr[4][4];
  #pragma unroll
  for (int T = 0; T < 4; ++T)
    #pragma unroll
    for (int j = 0; j < 4; ++j) thrr[T][j] = thr[T * 16 + kq * 4 + j];

  cb0.u = cbB[ct0 * 128 + lane * 2 + 0];
  cb1.u = cbB[ct0 * 128 + lane * 2 + 1];
  #pragma unroll 1
  for (int q = 0; q < 8; ++q) {
    const int ct = ct0 + q;
    if (q < 7) {
      nb0.u = cbB[(ct + 1) * 128 + lane * 2 + 0];
      nb1.u = cbB[(ct + 1) * 128 + lane * 2 + 1];
    }
    const float c2v = c2s[ct * 16 + m];
    const int k = ct * 16 + m;
    #pragma unroll
    for (int T = 0; T < 4; ++T) {
      f32x4 acc = {0.f, 0.f, 0.f, 0.f};
      acc = __builtin_amdgcn_mfma_f32_16x16x32_bf16(af0[T], cb0.h, acc, 0, 0, 0);
      acc = __builtin_amdgcn_mfma_f32_16x16x32_bf16(af1[T], cb1.h, acc, 0, 0, 0);
      #pragma unroll
      for (int j = 0; j < 4; ++j) {
        const float s = (x2r[T][j] - 2.0f * acc[j]) + c2v;
        if (s <= thrr[T][j]) {
          const int rr = T * 16 + kq * 4 + j;
          const int pos = atomicAdd(&cand_cnt[rr], 1);
          if (pos < 16) cand_k[rr][pos] = k;
        }
      }
    }
    cb0 = nb0;
    cb1 = nb1;
  }
  __syncthreads();

  // ---- exact rescore: 4 threads per row (phase = t>>6), candidates strided ----
  {
    const int rr = t & 63;
    const int ph = t >> 6;
    const int cnt = cand_cnt[rr];
    float bv = __builtin_inff();
    int bk = 0x7fffffff;
    if (cnt <= 16) {
      const float* xr = xs + rr * XS_STRIDE;
      const float x2e = x2s[rr];
      for (int c = ph; c < cnt; c += 4) {
        const int k = cand_k[rr][c];
        const float M = exact_dot(xr, codebook + k * DIMS);
        const float s = (x2e - 2.0f * M) + c2s[k];
        if (s < bv || (s == bv && k < bk)) { bv = s; bk = k; }
      }
    } else if (ph == 0) {
      const int p = atomicAdd(&ovf_cnt, 1);
      ovf_rows[p] = rr;
    }
    pvv[ph][rr] = bv;
    pkk[ph][rr] = bk;
  }
  __syncthreads();
  if (t < 64) {
    float bv = pvv[0][t];
    int bk = pkk[0][t];
    #pragma unroll
    for (int ph = 1; ph < 4; ++ph) {
      const float v = pvv[ph][t];
      const int k = pkk[ph][t];
      if (v < bv || (v == bv && k < bk)) { bv = v; bk = k; }
    }
    rowk[t] = bk;
  }
  __syncthreads();

  // overflow rows (rare): exact wave-parallel full scan by wave 0
  if (w == 0) {
    const int no = ovf_cnt;
    for (int o = 0; o < no; ++o) {
      const int rr = ovf_rows[o];
      const float* xr = xs + rr * XS_STRIDE;
      const float x2e = x2s[rr];
      float bv = __builtin_inff();
      int bk = 0x7fffffff;
      for (int k = lane; k < K_CODES; k += 64) {
        const float M = exact_dot(xr, codebook + k * DIMS);
        const float s = (x2e - 2.0f * M) + c2s[k];
        if (s < bv || (s == bv && k < bk)) { bv = s; bk = k; }
      }
      #pragma unroll
      for (int off = 1; off < 64; off <<= 1) {
        const float ov = __shfl_xor(bv, off);
        const int oi = __shfl_xor(bk, off);
        if (ov < bv || (ov == bv && oi < bk)) { bv = ov; bk = oi; }
      }
      if (lane == 0) rowk[rr] = bk;
    }
  }
  __syncthreads();

  // ---- outputs: codes + bins + fused STE/loss epilogue ----
  if (t < 64) {
    const int k = rowk[t];
    out_codes[row0 + t] = (float)k;
    atomicAdd(&bins[k], 1);
  }
  double dacc = 0.0;
  {
    float4* dst = (float4*)out_st + (size_t)row0 * 16;
    #pragma unroll
    for (int p = 0; p < 4; ++p) {
      const int f = p * 256 + t;
      const int r = f >> 4;
      const int d4 = f & 15;
      const int k = rowk[r];
      const float4 q = *(const float4*)&codebook[k * DIMS + d4 * 4];
      const float4 l = *(const float4*)&xs[r * XS_STRIDE + d4 * 4];
      float4 o;
      o.x = l.x + (q.x - l.x);  // straight-through, np rounding order
      o.y = l.y + (q.y - l.y);
      o.z = l.z + (q.z - l.z);
      o.w = l.w + (q.w - l.w);
      dst[f] = o;
      const float dx = l.x - q.x, dy = l.y - q.y, dz = l.z - q.z, dw = l.w - q.w;
      dacc += (double)dx * (double)dx;
      dacc += (double)dy * (double)dy;
      dacc += (double)dz * (double)dz;
      dacc += (double)dw * (double)dw;
    }
  }
  #pragma unroll
  for (int off = 32; off > 0; off >>= 1) dacc += __shfl_down(dacc, off);
  if (lane == 0) wsum[w] = dacc;
  __syncthreads();
  if (t == 0) loss_part[blockIdx.x] = (wsum[0] + wsum[1]) + (wsum[2] + wsum[3]);
}

// ---------------- K3: reduce loss partials + perplexity + scalar outputs ----------
__global__ __launch_bounds__(512) void vq_finalize(const int* __restrict__ bins,
                                                   const double* __restrict__ loss_part,
                                                   float* __restrict__ out3) {
  __shared__ double red[512];
  __shared__ double redl[512];
  const int t = threadIdx.x;
  const double p = (double)bins[t] / 131072.0;
  red[t] = -p * log(p + 1e-10);
  redl[t] = (loss_part[t] + loss_part[t + 512]) + (loss_part[t + 1024] + loss_part[t + 1536]);
  __syncthreads();
  for (int s = 256; s > 0; s >>= 1) {
    if (t < s) { red[t] += red[t + s]; redl[t] += redl[t + s]; }
    __syncthreads();
  }
  if (t == 0) {
    const double mean = redl[0] / 8388608.0;
    out3[0] = (float)(0.25 * mean);  // commitment * COMMITMENT_COST
    out3[1] = (float)mean;           // codebook_loss (same squares bitwise)
    out3[2] = (float)exp(red[0]);    // perplexity
  }
}

extern "C" void kernel_launch(void* const* d_in, const int* in_sizes, int n_in,
                              void* d_out, int out_size, void* d_ws, size_t ws_size,
                              hipStream_t stream) {
  const float* latents = (const float*)d_in[0];
  const float* codebook = (const float*)d_in[1];

  float* out = (float*)d_out;
  float* out_st = out;                              // 8388608
  float* out_codes = out + (size_t)N_ROWS * DIMS;   // 131072 (codes as float)
  float* out3 = out_codes + N_ROWS;                 // 3 scalars

  char* ws = (char*)d_ws;
  double* loss_part = (double*)ws;                  // [0, 16384)       2048 doubles
  int* bins = (int*)(ws + 16384);                   // [16384, 18432)
  float* c2g = (float*)(ws + 18432);                // [18432, 20480)
  float* cmax2 = (float*)(ws + 20480);              // [20480, 20484)
  uint4* cbB = (uint4*)(ws + 21504);                // [21504, 87040)   64 KB bf16 frags

  hipLaunchKernelGGL(vq_init, dim3(16), dim3(256), 0, stream,
                     codebook, bins, c2g, cmax2, cbB);
  hipLaunchKernelGGL(vq_main, dim3(2048), dim3(256), 0, stream,
                     latents, codebook, cbB, c2g, cmax2, out_st, out_codes, bins, loss_part);
  hipLaunchKernelGGL(vq_finalize, dim3(1), dim3(512), 0, stream,
                     bins, loss_part, out3);
}

// Round 8
// 140.560 us; speedup vs baseline: 20.1739x; 1.0857x over previous
//
#include <hip/hip_runtime.h>
#include <math.h>

#define N_ROWS 131072
#define DIMS 64
#define K_CODES 512
#define XS_STRIDE 68

typedef __attribute__((ext_vector_type(8))) short bf16x8;
typedef __attribute__((ext_vector_type(4))) float f32x4;

union B8 { uint4 u; bf16x8 h; };

// RNE float->bf16 pack (two floats -> one uint, low=first)
__device__ inline unsigned bpack(float a, float b) {
  unsigned ua = __float_as_uint(a), ub = __float_as_uint(b);
  ua = (ua + 0x7FFFu + ((ua >> 16) & 1u)) >> 16;
  ub = (ub + 0x7FFFu + ((ub >> 16) & 1u)) >> 16;
  return ua | (ub << 16);
}

// exact reference dot: single fmaf chain over ascending d (bitwise as prior rounds)
__device__ inline float exact_dot(const float* __restrict__ xr, const float* __restrict__ cr) {
  float m = 0.f;
  #pragma unroll
  for (int d4 = 0; d4 < 16; ++d4) {
    const float4 c = *(const float4*)&cr[d4 * 4];
    const float4 x = *(const float4*)&xr[d4 * 4];
    m = fmaf(x.x, c.x, m);
    m = fmaf(x.y, c.y, m);
    m = fmaf(x.z, c.z, m);
    m = fmaf(x.w, c.w, m);
  }
  return m;
}

// ---------------- K0 (64 blocks, fully parallel): bins zero + exact c2 + bf16(-2c) frags
// cbB layout (as passing rounds): entry e = ct*128 + lane*2 + half;
//   code = ct*16 + (lane&15), dims [(lane>>4)*8 + half*32 .. +8). Values are bf16(-2c):
//   folds the "-2" of d2 = x2 - 2M + c2 into the table (exact rel-err <= 2^-9 of -2c).
__global__ __launch_bounds__(256) void vq_init(const float* __restrict__ codebook,
                                               int* __restrict__ bins,
                                               float* __restrict__ c2g,
                                               uint4* __restrict__ cbB) {
  #pragma clang fp contract(off)
  const int t = threadIdx.x;
  const int b = blockIdx.x;
  if (t < 64) {
    const int e = b * 64 + t;          // 64 blocks x 64 = 4096 entries
    const int ct = e >> 7;
    const int q = e & 127;
    const int lane_id = q >> 1;
    const int half = q & 1;
    const int code = ct * 16 + (lane_id & 15);
    const int dbase = ((lane_id >> 4) * 8) + half * 32;
    const float* src = codebook + code * DIMS + dbase;
    const float4 a = *(const float4*)&src[0];
    const float4 c = *(const float4*)&src[4];
    uint4 u;
    u.x = bpack(-2.f * a.x, -2.f * a.y);
    u.y = bpack(-2.f * a.z, -2.f * a.w);
    u.z = bpack(-2.f * c.x, -2.f * c.y);
    u.w = bpack(-2.f * c.z, -2.f * c.w);
    cbB[e] = u;
  } else if (t < 72) {
    // exact c2: numpy pairwise_sum, n=64 (bitwise as prior passing rounds)
    const int k = b * 8 + (t - 64);
    const float* cr = codebook + k * DIMS;
    float r[8];
    #pragma unroll
    for (int j = 0; j < 8; ++j) r[j] = cr[j] * cr[j];
    for (int i = 8; i < 64; i += 8) {
      #pragma unroll
      for (int j = 0; j < 8; ++j) r[j] += cr[i + j] * cr[i + j];  // contract OFF
    }
    c2g[k] = ((r[0] + r[1]) + (r[2] + r[3])) + ((r[4] + r[5]) + (r[6] + r[7]));
  } else if (t < 80) {
    bins[b * 8 + (t - 72)] = 0;
  }
}

// ---------------- K1: MFMA approx scores -> candidates -> exact rescore -> outputs
// Grid 2048 x 256 (64 rows/block). Wave w covers all 64 rows (4 M-tiles) x its code
// quarter (8 tiles). Score trick: B holds bf16(-2c), MFMA C-input initialized to c2
// (C/D col=code so all 4 row-slots share c2v) -> MFMA output IS the score c2-2M^:
// sweep1 = 1 fmin/score, sweep2 = 1 cmp/score. Depth-2 named-set B prefetch covers L2
// latency. x2 (exact, for thr + rescore) computed 4-threads/row with the exact numpy
// pairwise tree split. Exact fmaf-chain rescore over candidates (bit-identical to all
// prior passing rounds) picks the true first-min winner; overflow -> exact full scan.
__global__ __launch_bounds__(256, 4) void vq_main(const float* __restrict__ latents,
                                                  const float* __restrict__ codebook,
                                                  const uint4* __restrict__ cbB,
                                                  const float* __restrict__ c2g,
                                                  float* __restrict__ out_st,
                                                  float* __restrict__ out_codes,
                                                  int* __restrict__ bins,
                                                  double* __restrict__ loss_part) {
  #pragma clang fp contract(off)
  __shared__ __align__(16) float xs[64 * XS_STRIDE];  // 17408 B
  __shared__ float x2p[64][4];
  __shared__ float x2s[64];
  __shared__ float c2s[K_CODES];
  __shared__ float wmaxs[4];
  __shared__ float thr[64];
  __shared__ float pmin[4][64];
  __shared__ int cand_cnt[64];
  __shared__ int cand_k[64][16];
  __shared__ int rowk[64];
  __shared__ float pvv[4][64];
  __shared__ int pkk[4][64];
  __shared__ int ovf_rows[64];
  __shared__ int ovf_cnt;
  __shared__ double wsum[4];

  const int t = threadIdx.x;
  const int lane = t & 63;
  const int w = t >> 6;
  const int m = lane & 15;
  const int kq = lane >> 4;
  const int row0 = blockIdx.x * 64;

  // phase 0: stage latents tile (coalesced) + c2 + zero counters
  {
    const float4* src = (const float4*)(latents + (size_t)row0 * DIMS);
    #pragma unroll
    for (int p = 0; p < 4; ++p) {
      const int f = p * 256 + t;
      *(float4*)&xs[(f >> 4) * XS_STRIDE + (f & 15) * 4] = src[f];
    }
    c2s[t] = c2g[t];
    c2s[t + 256] = c2g[t + 256];
    if (t < 64) cand_cnt[t] = 0;
    if (t == 0) ovf_cnt = 0;
  }
  __syncthreads();

  // phase 1: exact x2 partials (4 threads/row; numpy pairwise split — bitwise tree):
  // thread ph owns chains r[2ph], r[2ph+1]; partial = r[2ph]+r[2ph+1] (level-1 add).
  {
    const int rr = t >> 2, ph = t & 3;
    const float* xr = xs + rr * XS_STRIDE;
    float2 v = *(const float2*)&xr[2 * ph];
    float ra = v.x * v.x, rb = v.y * v.y;
    #pragma unroll
    for (int i8 = 1; i8 < 8; ++i8) {
      v = *(const float2*)&xr[i8 * 8 + 2 * ph];
      ra += v.x * v.x;
      rb += v.y * v.y;
    }
    x2p[rr][ph] = ra + rb;
  }
  // cmax2 partial per wave (from staged c2s — replaces vq_init's global reduction)
  {
    float mm = fmaxf(c2s[t], c2s[t + 256]);
    #pragma unroll
    for (int off = 1; off < 64; off <<= 1) mm = fmaxf(mm, __shfl_xor(mm, off));
    if (lane == 0) wmaxs[w] = mm;
  }
  __syncthreads();
  if (t < 64) x2s[t] = (x2p[t][0] + x2p[t][1]) + (x2p[t][2] + x2p[t][3]);
  // (x2s consumed only after sweep1's barrier — no extra barrier needed)

  // A fragments for all 4 M-tiles: lane holds A[row=T*16+m][k=kq*8+j] (+32 for frag1)
  bf16x8 af0[4], af1[4];
  #pragma unroll
  for (int T = 0; T < 4; ++T) {
    const float* xr = xs + (T * 16 + m) * XS_STRIDE + kq * 8;
    const float4 a0 = *(const float4*)&xr[0];
    const float4 a1 = *(const float4*)&xr[4];
    const float4 b0 = *(const float4*)&xr[32];
    const float4 b1 = *(const float4*)&xr[36];
    B8 pa, pb;
    pa.u.x = bpack(a0.x, a0.y); pa.u.y = bpack(a0.z, a0.w);
    pa.u.z = bpack(a1.x, a1.y); pa.u.w = bpack(a1.z, a1.w);
    pb.u.x = bpack(b0.x, b0.y); pb.u.y = bpack(b0.z, b0.w);
    pb.u.z = bpack(b1.x, b1.y); pb.u.w = bpack(b1.z, b1.w);
    af0[T] = pa.h;
    af1[T] = pb.h;
  }

  const int ct0 = w * 8;

  // ---- sweep 1: per-row approx min over this wave's code quarter ----
  float mv[4][4];
  #pragma unroll
  for (int T = 0; T < 4; ++T)
    #pragma unroll
    for (int j = 0; j < 4; ++j) mv[T][j] = __builtin_inff();

  {
    B8 sa0, sb0, sa1, sb1;
    sa0.u = cbB[(ct0 + 0) * 128 + lane * 2 + 0];
    sb0.u = cbB[(ct0 + 0) * 128 + lane * 2 + 1];
    sa1.u = cbB[(ct0 + 1) * 128 + lane * 2 + 0];
    sb1.u = cbB[(ct0 + 1) * 128 + lane * 2 + 1];
    #pragma unroll 1
    for (int qq = 0; qq < 4; ++qq) {
      const int ct = ct0 + qq * 2;
      {
        B8 na, nb;
        if (qq < 3) {
          na.u = cbB[(ct + 2) * 128 + lane * 2 + 0];
          nb.u = cbB[(ct + 2) * 128 + lane * 2 + 1];
        }
        const float c2v = c2s[ct * 16 + m];
        #pragma unroll
        for (int T = 0; T < 4; ++T) {
          f32x4 acc = {c2v, c2v, c2v, c2v};  // C-init = c2 -> acc ends as the score
          acc = __builtin_amdgcn_mfma_f32_16x16x32_bf16(af0[T], sa0.h, acc, 0, 0, 0);
          acc = __builtin_amdgcn_mfma_f32_16x16x32_bf16(af1[T], sb0.h, acc, 0, 0, 0);
          #pragma unroll
          for (int j = 0; j < 4; ++j) mv[T][j] = fminf(mv[T][j], acc[j]);
        }
        if (qq < 3) { sa0 = na; sb0 = nb; }
      }
      {
        B8 na, nb;
        if (qq < 3) {
          na.u = cbB[(ct + 3) * 128 + lane * 2 + 0];
          nb.u = cbB[(ct + 3) * 128 + lane * 2 + 1];
        }
        const float c2v = c2s[(ct + 1) * 16 + m];
        #pragma unroll
        for (int T = 0; T < 4; ++T) {
          f32x4 acc = {c2v, c2v, c2v, c2v};
          acc = __builtin_amdgcn_mfma_f32_16x16x32_bf16(af0[T], sa1.h, acc, 0, 0, 0);
          acc = __builtin_amdgcn_mfma_f32_16x16x32_bf16(af1[T], sb1.h, acc, 0, 0, 0);
          #pragma unroll
          for (int j = 0; j < 4; ++j) mv[T][j] = fminf(mv[T][j], acc[j]);
        }
        if (qq < 3) { sa1 = na; sb1 = nb; }
      }
    }
  }
  // reduce min across the 16 lanes sharing rows (xor 1,2,4,8 flips m only)
  #pragma unroll
  for (int T = 0; T < 4; ++T)
    #pragma unroll
    for (int j = 0; j < 4; ++j) {
      float v = mv[T][j];
      #pragma unroll
      for (int off = 1; off < 16; off <<= 1) v = fminf(v, __shfl_xor(v, off));
      mv[T][j] = v;
    }
  if (m == 0) {
    #pragma unroll
    for (int T = 0; T < 4; ++T)
      #pragma unroll
      for (int j = 0; j < 4; ++j) pmin[w][T * 16 + kq * 4 + j] = mv[T][j];
  }
  __syncthreads();
  if (t < 64) {
    const float gmin = fminf(fminf(pmin[0][t], pmin[1][t]), fminf(pmin[2][t], pmin[3][t]));
    const float cmax2 = fmaxf(fmaxf(wmaxs[0], wmaxs[1]), fmaxf(wmaxs[2], wmaxs[3]));
    // two-sided rigorous bf16 margin: 2 * 2^-7 * ||x|| * cmax (+ slack for fp32 ulps)
    thr[t] = gmin + (sqrtf(x2s[t]) * sqrtf(cmax2) * 0.0157f + 1e-3f);
  }
  __syncthreads();

  // ---- sweep 2: deterministic recompute, collect candidates (1 cmp/score) ----
  {
    float thrr[4][4];
    #pragma unroll
    for (int T = 0; T < 4; ++T)
      #pragma unroll
      for (int j = 0; j < 4; ++j) thrr[T][j] = thr[T * 16 + kq * 4 + j];

    B8 sa0, sb0, sa1, sb1;
    sa0.u = cbB[(ct0 + 0) * 128 + lane * 2 + 0];
    sb0.u = cbB[(ct0 + 0) * 128 + lane * 2 + 1];
    sa1.u = cbB[(ct0 + 1) * 128 + lane * 2 + 0];
    sb1.u = cbB[(ct0 + 1) * 128 + lane * 2 + 1];
    #pragma unroll 1
    for (int qq = 0; qq < 4; ++qq) {
      const int ct = ct0 + qq * 2;
      {
        B8 na, nb;
        if (qq < 3) {
          na.u = cbB[(ct + 2) * 128 + lane * 2 + 0];
          nb.u = cbB[(ct + 2) * 128 + lane * 2 + 1];
        }
        const float c2v = c2s[ct * 16 + m];
        const int k = ct * 16 + m;
        #pragma unroll
        for (int T = 0; T < 4; ++T) {
          f32x4 acc = {c2v, c2v, c2v, c2v};
          acc = __builtin_amdgcn_mfma_f32_16x16x32_bf16(af0[T], sa0.h, acc, 0, 0, 0);
          acc = __builtin_amdgcn_mfma_f32_16x16x32_bf16(af1[T], sb0.h, acc, 0, 0, 0);
          #pragma unroll
          for (int j = 0; j < 4; ++j) {
            if (acc[j] <= thrr[T][j]) {
              const int rr = T * 16 + kq * 4 + j;
              const int pos = atomicAdd(&cand_cnt[rr], 1);
              if (pos < 16) cand_k[rr][pos] = k;
            }
          }
        }
        if (qq < 3) { sa0 = na; sb0 = nb; }
      }
      {
        B8 na, nb;
        if (qq < 3) {
          na.u = cbB[(ct + 3) * 128 + lane * 2 + 0];
          nb.u = cbB[(ct + 3) * 128 + lane * 2 + 1];
        }
        const float c2v = c2s[(ct + 1) * 16 + m];
        const int k = (ct + 1) * 16 + m;
        #pragma unroll
        for (int T = 0; T < 4; ++T) {
          f32x4 acc = {c2v, c2v, c2v, c2v};
          acc = __builtin_amdgcn_mfma_f32_16x16x32_bf16(af0[T], sa1.h, acc, 0, 0, 0);
          acc = __builtin_amdgcn_mfma_f32_16x16x32_bf16(af1[T], sb1.h, acc, 0, 0, 0);
          #pragma unroll
          for (int j = 0; j < 4; ++j) {
            if (acc[j] <= thrr[T][j]) {
              const int rr = T * 16 + kq * 4 + j;
              const int pos = atomicAdd(&cand_cnt[rr], 1);
              if (pos < 16) cand_k[rr][pos] = k;
            }
          }
        }
        if (qq < 3) { sa1 = na; sb1 = nb; }
      }
    }
  }
  __syncthreads();

  // ---- exact rescore: 4 threads per row (phase = t>>6), candidates strided ----
  {
    const int rr = t & 63;
    const int ph = t >> 6;
    const int cnt = cand_cnt[rr];
    float bv = __builtin_inff();
    int bk = 0x7fffffff;
    if (cnt <= 16) {
      const float* xr = xs + rr * XS_STRIDE;
      const float x2e = x2s[rr];
      for (int c = ph; c < cnt; c += 4) {
        const int k = cand_k[rr][c];
        const float M = exact_dot(xr, codebook + k * DIMS);
        const float s = (x2e - 2.0f * M) + c2s[k];
        if (s < bv || (s == bv && k < bk)) { bv = s; bk = k; }
      }
    } else if (ph == 0) {
      const int p = atomicAdd(&ovf_cnt, 1);
      ovf_rows[p] = rr;
    }
    pvv[ph][rr] = bv;
    pkk[ph][rr] = bk;
  }
  __syncthreads();
  if (t < 64) {
    float bv = pvv[0][t];
    int bk = pkk[0][t];
    #pragma unroll
    for (int ph = 1; ph < 4; ++ph) {
      const float v = pvv[ph][t];
      const int k = pkk[ph][t];
      if (v < bv || (v == bv && k < bk)) { bv = v; bk = k; }
    }
    rowk[t] = bk;
  }
  __syncthreads();

  // overflow rows (rare): exact wave-parallel full scan by wave 0
  if (w == 0) {
    const int no = ovf_cnt;
    for (int o = 0; o < no; ++o) {
      const int rr = ovf_rows[o];
      const float* xr = xs + rr * XS_STRIDE;
      const float x2e = x2s[rr];
      float bv = __builtin_inff();
      int bk = 0x7fffffff;
      for (int k = lane; k < K_CODES; k += 64) {
        const float M = exact_dot(xr, codebook + k * DIMS);
        const float s = (x2e - 2.0f * M) + c2s[k];
        if (s < bv || (s == bv && k < bk)) { bv = s; bk = k; }
      }
      #pragma unroll
      for (int off = 1; off < 64; off <<= 1) {
        const float ov = __shfl_xor(bv, off);
        const int oi = __shfl_xor(bk, off);
        if (ov < bv || (ov == bv && oi < bk)) { bv = ov; bk = oi; }
      }
      if (lane == 0) rowk[rr] = bk;
    }
  }
  __syncthreads();

  // ---- outputs: codes + bins + fused STE/loss epilogue ----
  if (t < 64) {
    const int k = rowk[t];
    out_codes[row0 + t] = (float)k;
    atomicAdd(&bins[k], 1);
  }
  double dacc = 0.0;
  {
    float4* dst = (float4*)out_st + (size_t)row0 * 16;
    #pragma unroll
    for (int p = 0; p < 4; ++p) {
      const int f = p * 256 + t;
      const int r = f >> 4;
      const int d4 = f & 15;
      const int k = rowk[r];
      const float4 q = *(const float4*)&codebook[k * DIMS + d4 * 4];
      const float4 l = *(const float4*)&xs[r * XS_STRIDE + d4 * 4];
      float4 o;
      o.x = l.x + (q.x - l.x);  // straight-through, np rounding order
      o.y = l.y + (q.y - l.y);
      o.z = l.z + (q.z - l.z);
      o.w = l.w + (q.w - l.w);
      dst[f] = o;
      const float dx = l.x - q.x, dy = l.y - q.y, dz = l.z - q.z, dw = l.w - q.w;
      dacc += (double)dx * (double)dx;
      dacc += (double)dy * (double)dy;
      dacc += (double)dz * (double)dz;
      dacc += (double)dw * (double)dw;
    }
  }
  #pragma unroll
  for (int off = 32; off > 0; off >>= 1) dacc += __shfl_down(dacc, off);
  if (lane == 0) wsum[w] = dacc;
  __syncthreads();
  if (t == 0) loss_part[blockIdx.x] = (wsum[0] + wsum[1]) + (wsum[2] + wsum[3]);
}

// ---------------- K3: reduce loss partials + perplexity + scalar outputs ----------
__global__ __launch_bounds__(512) void vq_finalize(const int* __restrict__ bins,
                                                   const double* __restrict__ loss_part,
                                                   float* __restrict__ out3) {
  __shared__ double red[512];
  __shared__ double redl[512];
  const int t = threadIdx.x;
  const double p = (double)bins[t] / 131072.0;
  red[t] = -p * log(p + 1e-10);
  redl[t] = (loss_part[t] + loss_part[t + 512]) + (loss_part[t + 1024] + loss_part[t + 1536]);
  __syncthreads();
  for (int s = 256; s > 0; s >>= 1) {
    if (t < s) { red[t] += red[t + s]; redl[t] += redl[t + s]; }
    __syncthreads();
  }
  if (t == 0) {
    const double mean = redl[0] / 8388608.0;
    out3[0] = (float)(0.25 * mean);  // commitment * COMMITMENT_COST
    out3[1] = (float)mean;           // codebook_loss (same squares bitwise)
    out3[2] = (float)exp(red[0]);    // perplexity
  }
}

extern "C" void kernel_launch(void* const* d_in, const int* in_sizes, int n_in,
                              void* d_out, int out_size, void* d_ws, size_t ws_size,
                              hipStream_t stream) {
  const float* latents = (const float*)d_in[0];
  const float* codebook = (const float*)d_in[1];

  float* out = (float*)d_out;
  float* out_st = out;                              // 8388608
  float* out_codes = out + (size_t)N_ROWS * DIMS;   // 131072 (codes as float)
  float* out3 = out_codes + N_ROWS;                 // 3 scalars

  char* ws = (char*)d_ws;
  double* loss_part = (double*)ws;                  // [0, 16384)       2048 doubles
  int* bins = (int*)(ws + 16384);                   // [16384, 18432)
  float* c2g = (float*)(ws + 18432);                // [18432, 20480)
  uint4* cbB = (uint4*)(ws + 21504);                // [21504, 87040)   64 KB bf16(-2c)

  hipLaunchKernelGGL(vq_init, dim3(64), dim3(256), 0, stream,
                     codebook, bins, c2g, cbB);
  hipLaunchKernelGGL(vq_main, dim3(2048), dim3(256), 0, stream,
                     latents, codebook, cbB, c2g, out_st, out_codes, bins, loss_part);
  hipLaunchKernelGGL(vq_finalize, dim3(1), dim3(512), 0, stream,
                     bins, loss_part, out3);
}